// Round 1
// baseline (29255.072 us; speedup 1.0000x reference)
//
#include <hip/hip_runtime.h>
#include <hip/hip_bf16.h>
#include <stdint.h>

// ResRnn persistent kernel for MI355X.
// 1024 sequential steps; weight-stationary 2D partition:
//   8 row-groups (32 batch rows each) x 32 col-blocks (32 stream cols each) = 256 WGs (1/CU).
// Each WG holds its W1/W2 slices (32x1024 bf16 each, XOR-swizzled) in 128 KiB LDS for the
// whole run. Per step: phase1 h=|s@W1^T+b1| (group barrier) phase2 s'=p*s+(1-p)(h@W2^T+b2).
// Activations exchanged via L2/L3 with agent-scope release/acquire flag barriers per group.
// fp32 master copy of the stream (ping-pong) keeps the residual path exact; only MFMA
// inputs are bf16.

#define NSTEP  1024
#define BATCH  256
#define INSZ   64
#define SSZ    1024

#define GROUPS 8
#define CBLKS  32
#define RPG    32   // rows per group  (BATCH/GROUPS)
#define CPB    32   // cols per block  (SSZ/CBLKS)

typedef __bf16 bf16x8 __attribute__((ext_vector_type(8)));
typedef float  f32x4  __attribute__((ext_vector_type(4)));

// Flag barrier among the 32 WGs of a row-group. Epochs are strictly increasing
// (1,2,3,...); readers accept flag >= epoch via wraparound-safe signed diff, so
// 0xAAAAAAAA poison reads as "not yet" and an overtaking peer can't deadlock us.
__device__ __forceinline__ void group_barrier(unsigned* flags, int g, int c,
                                              unsigned e, int tid)
{
    __syncthreads();  // drains vmcnt for all waves -> all our stores are in L2
    if (tid == 0)
        __hip_atomic_store(&flags[g * CBLKS + c], e, __ATOMIC_RELEASE,
                           __HIP_MEMORY_SCOPE_AGENT);  // wb L2, publish flag to L3
    if (tid < 64) {  // wave 0 spins; lanes 0..31 poll the 32 peer flags
        uint64_t t0 = __builtin_amdgcn_s_memrealtime();
        for (;;) {
            unsigned v = e;
            if (tid < CBLKS)
                v = __hip_atomic_load(&flags[g * CBLKS + tid], __ATOMIC_RELAXED,
                                      __HIP_MEMORY_SCOPE_AGENT);
            if (!__any((int)(v - e) < 0)) break;
            if (__builtin_amdgcn_s_memrealtime() - t0 > 4000000ull) break; // ~40ms bail-out
        }
        __threadfence();  // acquire: invalidate L1/L2 so peers' data is re-fetched
    }
    __syncthreads();
}

// One 16x16 output tile over K=1024: A fragments straight from global (L2),
// B fragments from XOR-swizzled LDS. 4 interleaved K-partials break the
// dependent-MFMA chain; summed at the end (fp32).
__device__ __forceinline__ f32x4 mm16x16(const __bf16* A0, const char* B0,
                                         int swz, int koff, int kbyte)
{
    f32x4 z = {0.f, 0.f, 0.f, 0.f};
    f32x4 acc0 = z, acc1 = z, acc2 = z, acc3 = z;
    const bf16x8* Ap = reinterpret_cast<const bf16x8*>(A0 + koff);
    #pragma unroll
    for (int kc = 0; kc < 32; kc += 4) {
        bf16x8 a0 = Ap[(kc + 0) * 4];
        bf16x8 a1 = Ap[(kc + 1) * 4];
        bf16x8 a2 = Ap[(kc + 2) * 4];
        bf16x8 a3 = Ap[(kc + 3) * 4];
        bf16x8 w0 = *reinterpret_cast<const bf16x8*>(B0 + ((((kc + 0) * 64) + kbyte) ^ swz));
        bf16x8 w1 = *reinterpret_cast<const bf16x8*>(B0 + ((((kc + 1) * 64) + kbyte) ^ swz));
        bf16x8 w2 = *reinterpret_cast<const bf16x8*>(B0 + ((((kc + 2) * 64) + kbyte) ^ swz));
        bf16x8 w3 = *reinterpret_cast<const bf16x8*>(B0 + ((((kc + 3) * 64) + kbyte) ^ swz));
        acc0 = __builtin_amdgcn_mfma_f32_16x16x32_bf16(a0, w0, acc0, 0, 0, 0);
        acc1 = __builtin_amdgcn_mfma_f32_16x16x32_bf16(a1, w1, acc1, 0, 0, 0);
        acc2 = __builtin_amdgcn_mfma_f32_16x16x32_bf16(a2, w2, acc2, 0, 0, 0);
        acc3 = __builtin_amdgcn_mfma_f32_16x16x32_bf16(a3, w3, acc3, 0, 0, 0);
    }
    return (acc0 + acc1) + (acc2 + acc3);
}

extern "C" __global__ void __launch_bounds__(256, 1)
resrnn_kernel(const float* __restrict__ x,  const float* __restrict__ W1,
              const float* __restrict__ b1, const float* __restrict__ W2,
              const float* __restrict__ b2,
              __bf16* sBuf, __bf16* hBuf, float* sf32, unsigned* flags,
              float* __restrict__ dout)
{
    extern __shared__ char smem[];
    char* W1s = smem;            // 64 KiB: [32 cols][1024 k] bf16, swizzled
    char* W2s = smem + 65536;    // 64 KiB

    const int tid = threadIdx.x;
    const int bid = blockIdx.x;
    const int g   = bid & 7;     // row group (blockIdx%8 -> XCD-local under round-robin)
    const int c   = bid >> 3;    // col block
    const int rb  = g * RPG;
    const int cb  = c * CPB;

    // ---- stage weight slices to LDS (fp32 -> bf16, XOR-swizzle k-offset by col) ----
    {
        const int lc  = tid >> 3;          // local col 0..31
        const int seg = (tid & 7) * 128;   // k start
        const int sw  = (lc & 7) << 4;
        const float* w1p = W1 + (size_t)(cb + lc) * SSZ + seg;
        const float* w2p = W2 + (size_t)(cb + lc) * SSZ + seg;
        char* d1 = W1s + lc * 2048;
        char* d2 = W2s + lc * 2048;
        #pragma unroll 4
        for (int kk = 0; kk < 16; ++kk) {
            const int kb = (seg + kk * 8) * 2;
            float4 f0 = reinterpret_cast<const float4*>(w1p)[kk * 2 + 0];
            float4 f1 = reinterpret_cast<const float4*>(w1p)[kk * 2 + 1];
            bf16x8 v;
            v[0] = (__bf16)f0.x; v[1] = (__bf16)f0.y; v[2] = (__bf16)f0.z; v[3] = (__bf16)f0.w;
            v[4] = (__bf16)f1.x; v[5] = (__bf16)f1.y; v[6] = (__bf16)f1.z; v[7] = (__bf16)f1.w;
            *reinterpret_cast<bf16x8*>(d1 + (kb ^ sw)) = v;
            f0 = reinterpret_cast<const float4*>(w2p)[kk * 2 + 0];
            f1 = reinterpret_cast<const float4*>(w2p)[kk * 2 + 1];
            v[0] = (__bf16)f0.x; v[1] = (__bf16)f0.y; v[2] = (__bf16)f0.z; v[3] = (__bf16)f0.w;
            v[4] = (__bf16)f1.x; v[5] = (__bf16)f1.y; v[6] = (__bf16)f1.z; v[7] = (__bf16)f1.w;
            *reinterpret_cast<bf16x8*>(d2 + (kb ^ sw)) = v;
        }
    }

    // ---- init our tile of the state: sBuf = s_0 = [x_0 | 0], SF32[0] = S_0 = 0 ----
    // (workspace is poisoned 0xAA before every launch -> must write everything we read)
    {
        const int e0  = tid * 4;
        const int row = rb + (e0 >> 5);
        const int col = cb + (e0 & 31);
        float4 z4 = {0.f, 0.f, 0.f, 0.f};
        *reinterpret_cast<float4*>(sf32 + (size_t)row * SSZ + col) = z4;
        __bf16* sp = sBuf + (size_t)row * SSZ + col;
        if (c < 2) {  // cols < 64 -> x_0
            const float* xp = x + (size_t)row * INSZ + col;
            sp[0] = (__bf16)xp[0]; sp[1] = (__bf16)xp[1];
            sp[2] = (__bf16)xp[2]; sp[3] = (__bf16)xp[3];
        } else {
            sp[0] = (__bf16)0.f; sp[1] = (__bf16)0.f;
            sp[2] = (__bf16)0.f; sp[3] = (__bf16)0.f;
        }
    }

    group_barrier(flags, g, c, 1u, tid);

    // ---- per-thread MFMA geometry (2x2 wave quadrants over the 32x32 WG tile) ----
    const int lane  = tid & 63;
    const int wv    = tid >> 6;
    const int mh    = wv >> 1;          // row half
    const int nh    = wv & 1;           // col half
    const int arow  = rb + mh * 16 + (lane & 15);       // A operand row
    const int kgrp  = lane >> 4;                        // k lane-group 0..3
    const int koff  = kgrp * 8;
    const int kbyte = kgrp * 16;
    const int lc    = nh * 16 + (lane & 15);            // local col 0..31
    const int swzB  = (lc & 7) << 4;
    const char* Bw1 = W1s + lc * 2048;
    const char* Bw2 = W2s + lc * 2048;
    const float bias1 = b1[cb + lc];
    const float bias2 = b2[cb + lc];
    const int drow0 = rb + mh * 16 + kgrp * 4;          // C/D row base (row=(l>>4)*4+j)
    const int dcol  = cb + lc;                          // C/D col     (col=l&15)
    const float P = 0.97f, OMP = 1.0f - 0.97f;

    const __bf16* Asrc1 = sBuf + (size_t)arow * SSZ;
    const __bf16* Asrc2 = hBuf + (size_t)arow * SSZ;

    for (int t = 0; t < NSTEP; ++t) {
        // ---- phase 1: h = |s @ W1^T + b1| (our 32x32 tile) ----
        f32x4 h4 = mm16x16(Asrc1, Bw1, swzB, koff, kbyte);
        #pragma unroll
        for (int j = 0; j < 4; ++j) {
            float hv = fabsf(h4[j] + bias1);
            hBuf[(size_t)(drow0 + j) * SSZ + dcol] = (__bf16)hv;
        }
        group_barrier(flags, g, c, (unsigned)(2 + 2 * t), tid);

        // ---- phase 2: S' = p*s + (1-p)*(h @ W2^T + b2); publish shifted s_{t+1} ----
        f32x4 u4 = mm16x16(Asrc2, Bw2, swzB, koff, kbyte);
        const float* srd = sf32 + (size_t)(t & 1) * (BATCH * SSZ);
        float*       swr = sf32 + (size_t)((t + 1) & 1) * (BATCH * SSZ);
        #pragma unroll
        for (int j = 0; j < 4; ++j) {
            const int row = drow0 + j;
            float sprev;
            if (c < 2)   // shifted-in x_t columns: exact fp32 from input
                sprev = x[(size_t)t * (BATCH * INSZ) + (size_t)row * INSZ + dcol];
            else         // S_t[:, col-64], fp32 master (written by WG(g,c-2) last step)
                sprev = srd[(size_t)row * SSZ + (dcol - 64)];
            const float snew = P * sprev + OMP * (u4[j] + bias2);
            swr[(size_t)row * SSZ + dcol] = snew;          // fp32 master for step t+1
            if (c < 30)                                    // shifted bf16 publish: block c+2
                sBuf[(size_t)row * SSZ + (dcol + 64)] = (__bf16)snew;
            else if (t == NSTEP - 1)                       // final output: S_1024[:, 960:]
                dout[row * 64 + (dcol - 960)] = snew;
        }
        if (c < 2 && t < NSTEP - 1) {  // blocks 0,1 of s_{t+1} = x_{t+1}
            #pragma unroll
            for (int j = 0; j < 4; ++j) {
                const int row = drow0 + j;
                sBuf[(size_t)row * SSZ + dcol] =
                    (__bf16)x[(size_t)(t + 1) * (BATCH * INSZ) + (size_t)row * INSZ + dcol];
            }
        }
        if (t < NSTEP - 1)
            group_barrier(flags, g, c, (unsigned)(3 + 2 * t), tid);
    }
}

extern "C" void kernel_launch(void* const* d_in, const int* in_sizes, int n_in,
                              void* d_out, int out_size, void* d_ws, size_t ws_size,
                              hipStream_t stream)
{
    const float* x  = (const float*)d_in[0];
    const float* W1 = (const float*)d_in[1];
    const float* b1 = (const float*)d_in[2];
    const float* W2 = (const float*)d_in[3];
    const float* b2 = (const float*)d_in[4];
    float* dout = (float*)d_out;

    char* ws = (char*)d_ws;
    __bf16*   sBuf  = (__bf16*)(ws);                 // 512 KiB: shifted s_t, bf16
    __bf16*   hBuf  = (__bf16*)(ws + (512 << 10));   // 512 KiB: h, bf16
    float*    sf32  = (float*)(ws + (1 << 20));      // 2 MiB: fp32 S ping-pong
    unsigned* flags = (unsigned*)(ws + (3 << 20));   // 1 KiB: 8 groups x 32 flags

    (void)in_sizes; (void)n_in; (void)out_size; (void)ws_size;

    hipFuncSetAttribute(reinterpret_cast<const void*>(&resrnn_kernel),
                        hipFuncAttributeMaxDynamicSharedMemorySize, 131072);
    hipLaunchKernelGGL(resrnn_kernel, dim3(256), dim3(256), 131072, stream,
                       x, W1, b1, W2, b2, sBuf, hBuf, sf32, flags, dout);
}

// Round 2
// 18724.217 us; speedup vs baseline: 1.5624x; 1.5624x over previous
//
#include <hip/hip_runtime.h>
#include <hip/hip_bf16.h>
#include <stdint.h>

// ResRnn persistent kernel for MI355X — round 2.
// Same weight-stationary 2D partition (8 row-groups x 32 col-blocks = 256 WGs, 1/CU;
// W1/W2 32x1024 bf16 slices LDS-resident, XOR-swizzled). Round-1 lesson: agent-scope
// release/acquire fences emit buffer_wbl2/buffer_inv -> 2.1 GB of fence-serialized HBM
// writeback (the whole 29 ms). This version keeps ALL cross-WG data out of dirty L2:
// every shared write is an sc0|sc1 write-through store, every shared read is an sc0|sc1
// L3-coherent load, and the flag barrier uses relaxed atomics + vmcnt drain only.
// A-operands are cooperatively staged via LDS (spare 32 KB) in two K=512 chunks,
// issue-early/write-late so chunk-1 loads overlap chunk-0 MFMAs.

#define NSTEP  1024
#define BATCH  256
#define INSZ   64
#define SSZ    1024

#define GROUPS 8
#define CBLKS  32
#define RPG    32   // rows per group
#define CPB    32   // cols per block
#define FPAD   16   // flag padding (16 u32 = 64 B per flag)

typedef __bf16 bf16x8 __attribute__((ext_vector_type(8)));
typedef float  f32x4  __attribute__((ext_vector_type(4)));

#define SCHED_FENCE() __builtin_amdgcn_sched_barrier(0)

// 8 contiguous 16B coherent loads (bypass L1+L2, served at Infinity Cache).
__device__ __forceinline__ void issue_stage8(const __bf16* p,
    bf16x8& r0, bf16x8& r1, bf16x8& r2, bf16x8& r3,
    bf16x8& r4, bf16x8& r5, bf16x8& r6, bf16x8& r7)
{
    asm volatile(
        "global_load_dwordx4 %0, %8, off sc0 sc1\n\t"
        "global_load_dwordx4 %1, %8, off offset:16 sc0 sc1\n\t"
        "global_load_dwordx4 %2, %8, off offset:32 sc0 sc1\n\t"
        "global_load_dwordx4 %3, %8, off offset:48 sc0 sc1\n\t"
        "global_load_dwordx4 %4, %8, off offset:64 sc0 sc1\n\t"
        "global_load_dwordx4 %5, %8, off offset:80 sc0 sc1\n\t"
        "global_load_dwordx4 %6, %8, off offset:96 sc0 sc1\n\t"
        "global_load_dwordx4 %7, %8, off offset:112 sc0 sc1"
        : "=v"(r0), "=v"(r1), "=v"(r2), "=v"(r3),
          "=v"(r4), "=v"(r5), "=v"(r6), "=v"(r7)
        : "v"(p) : "memory");
}

__device__ __forceinline__ void st_coh_u16(void* p, unsigned short v) {
    asm volatile("global_store_short %0, %1, off sc0 sc1" :: "v"(p), "v"(v) : "memory");
}
__device__ __forceinline__ void st_coh_f32(void* p, float v) {
    asm volatile("global_store_dword %0, %1, off sc0 sc1" :: "v"(p), "v"(v) : "memory");
}
// 4 scattered coherent dword loads, one latency.
__device__ __forceinline__ void ld_coh_f32x4s(const float* p0, const float* p1,
                                              const float* p2, const float* p3,
                                              float& r0, float& r1, float& r2, float& r3) {
    asm volatile(
        "global_load_dword %0, %4, off sc0 sc1\n\t"
        "global_load_dword %1, %5, off sc0 sc1\n\t"
        "global_load_dword %2, %6, off sc0 sc1\n\t"
        "global_load_dword %3, %7, off sc0 sc1\n\t"
        "s_waitcnt vmcnt(0)"
        : "=v"(r0), "=v"(r1), "=v"(r2), "=v"(r3)
        : "v"(p0), "v"(p1), "v"(p2), "v"(p3)
        : "memory");
}

// Flag barrier among the 32 WGs of a row-group. No fences: data already at L3 via
// sc0|sc1 write-through; vmcnt(0)+syncthreads => all waves' stores retired before the
// flag publishes. Epochs strictly increasing; signed-diff compare tolerates 0xAA poison.
__device__ __forceinline__ void group_barrier(unsigned* flags, int g, int c,
                                              unsigned e, int tid)
{
    asm volatile("s_waitcnt vmcnt(0)" ::: "memory");
    __syncthreads();
    if (tid == 0)
        __hip_atomic_store(&flags[(g * CBLKS + c) * FPAD], e, __ATOMIC_RELAXED,
                           __HIP_MEMORY_SCOPE_AGENT);
    if (tid < 64) {
        uint64_t t0 = __builtin_amdgcn_s_memrealtime();
        for (;;) {
            unsigned v = e;
            if (tid < CBLKS)
                v = __hip_atomic_load(&flags[(g * CBLKS + tid) * FPAD], __ATOMIC_RELAXED,
                                      __HIP_MEMORY_SCOPE_AGENT);
            if (!__any((int)(v - e) < 0)) break;
            if (__builtin_amdgcn_s_memrealtime() - t0 > 4000000ull) break; // ~40ms bail
        }
    }
    __syncthreads();
}

// One K=512 chunk: A fragments from staged LDS (swizzled), B from LDS weights.
// 4 interleaved K-partial accumulators.
__device__ __forceinline__ void mm_chunk(f32x4* acc, const char* As_rd, const char* Bw,
                                         int kbyte, int aswz, int bswz, int cb2)
{
    #pragma unroll
    for (int kc = 0; kc < 16; ++kc) {
        bf16x8 a = *reinterpret_cast<const bf16x8*>(As_rd + ((kc * 64 + kbyte) ^ aswz));
        bf16x8 w = *reinterpret_cast<const bf16x8*>(Bw + ((cb2 + kc * 64 + kbyte) ^ bswz));
        acc[kc & 3] = __builtin_amdgcn_mfma_f32_16x16x32_bf16(a, w, acc[kc & 3], 0, 0, 0);
    }
}

// Full phase: stage 32x1024 bf16 activation slice (2 chunks) + 32 MFMAs/wave.
__device__ __forceinline__ void run_phase(const __bf16* ssrc, char* As, int r, int o,
                                          const char* As_rd, const char* Bw,
                                          int kbyte, int aswz, int bswz, f32x4* acc)
{
    const int sw = (r & 7) << 4;
    char* const wrow = As + r * 1024;
    bf16x8 a0, a1, a2, a3, a4, a5, a6, a7;

    // chunk 0: k 0..511
    issue_stage8(ssrc, a0, a1, a2, a3, a4, a5, a6, a7);
    asm volatile("s_waitcnt vmcnt(0)" ::: "memory");
    SCHED_FENCE();
    *reinterpret_cast<bf16x8*>(wrow + ((o * 128 +   0) ^ sw)) = a0;
    *reinterpret_cast<bf16x8*>(wrow + ((o * 128 +  16) ^ sw)) = a1;
    *reinterpret_cast<bf16x8*>(wrow + ((o * 128 +  32) ^ sw)) = a2;
    *reinterpret_cast<bf16x8*>(wrow + ((o * 128 +  48) ^ sw)) = a3;
    *reinterpret_cast<bf16x8*>(wrow + ((o * 128 +  64) ^ sw)) = a4;
    *reinterpret_cast<bf16x8*>(wrow + ((o * 128 +  80) ^ sw)) = a5;
    *reinterpret_cast<bf16x8*>(wrow + ((o * 128 +  96) ^ sw)) = a6;
    *reinterpret_cast<bf16x8*>(wrow + ((o * 128 + 112) ^ sw)) = a7;
    __syncthreads();

    // chunk 1 loads fly while chunk 0 computes (syncthreads' vmcnt(0) drains them)
    issue_stage8(ssrc + 512, a0, a1, a2, a3, a4, a5, a6, a7);
    mm_chunk(acc, As_rd, Bw, kbyte, aswz, bswz, 0);
    __syncthreads();                       // everyone done reading chunk 0
    asm volatile("s_waitcnt vmcnt(0)" ::: "memory");
    SCHED_FENCE();
    *reinterpret_cast<bf16x8*>(wrow + ((o * 128 +   0) ^ sw)) = a0;
    *reinterpret_cast<bf16x8*>(wrow + ((o * 128 +  16) ^ sw)) = a1;
    *reinterpret_cast<bf16x8*>(wrow + ((o * 128 +  32) ^ sw)) = a2;
    *reinterpret_cast<bf16x8*>(wrow + ((o * 128 +  48) ^ sw)) = a3;
    *reinterpret_cast<bf16x8*>(wrow + ((o * 128 +  64) ^ sw)) = a4;
    *reinterpret_cast<bf16x8*>(wrow + ((o * 128 +  80) ^ sw)) = a5;
    *reinterpret_cast<bf16x8*>(wrow + ((o * 128 +  96) ^ sw)) = a6;
    *reinterpret_cast<bf16x8*>(wrow + ((o * 128 + 112) ^ sw)) = a7;
    __syncthreads();
    mm_chunk(acc, As_rd, Bw, kbyte, aswz, bswz, 1024);
}

extern "C" __global__ void __launch_bounds__(256, 1)
resrnn_kernel(const float* __restrict__ x,  const float* __restrict__ W1,
              const float* __restrict__ b1, const float* __restrict__ W2,
              const float* __restrict__ b2,
              __bf16* sBuf, __bf16* hBuf, float* sf32, unsigned* flags,
              float* __restrict__ dout)
{
    extern __shared__ char smem[];
    char* W1s = smem;             // 64 KiB: [32 cols][1024 k] bf16, swizzled
    char* W2s = smem + 65536;     // 64 KiB
    char* As  = smem + 131072;    // 32 KiB: staged A chunk [32 rows][512 k] bf16, swizzled

    const int tid = threadIdx.x;
    const int bid = blockIdx.x;
    const int g   = bid & 7;      // row group
    const int c   = bid >> 3;     // col block
    const int rb  = g * RPG;
    const int cb  = c * CPB;

    // ---- stage weight slices to LDS (fp32 -> bf16, XOR-swizzle by col) ----
    {
        const int lc  = tid >> 3;
        const int seg = (tid & 7) * 128;
        const int sw  = (lc & 7) << 4;
        const float* w1p = W1 + (size_t)(cb + lc) * SSZ + seg;
        const float* w2p = W2 + (size_t)(cb + lc) * SSZ + seg;
        char* d1 = W1s + lc * 2048;
        char* d2 = W2s + lc * 2048;
        #pragma unroll 4
        for (int kk = 0; kk < 16; ++kk) {
            const int kb = (seg + kk * 8) * 2;
            float4 f0 = reinterpret_cast<const float4*>(w1p)[kk * 2 + 0];
            float4 f1 = reinterpret_cast<const float4*>(w1p)[kk * 2 + 1];
            bf16x8 v;
            v[0] = (__bf16)f0.x; v[1] = (__bf16)f0.y; v[2] = (__bf16)f0.z; v[3] = (__bf16)f0.w;
            v[4] = (__bf16)f1.x; v[5] = (__bf16)f1.y; v[6] = (__bf16)f1.z; v[7] = (__bf16)f1.w;
            *reinterpret_cast<bf16x8*>(d1 + (kb ^ sw)) = v;
            f0 = reinterpret_cast<const float4*>(w2p)[kk * 2 + 0];
            f1 = reinterpret_cast<const float4*>(w2p)[kk * 2 + 1];
            v[0] = (__bf16)f0.x; v[1] = (__bf16)f0.y; v[2] = (__bf16)f0.z; v[3] = (__bf16)f0.w;
            v[4] = (__bf16)f1.x; v[5] = (__bf16)f1.y; v[6] = (__bf16)f1.z; v[7] = (__bf16)f1.w;
            *reinterpret_cast<bf16x8*>(d2 + (kb ^ sw)) = v;
        }
    }

    // ---- init our tile: sBuf = [x_0 | 0] (bf16), sf32[buf0] = 0 ----
    // all via coherent stores (ws is 0xAA-poisoned; consumers read via L3)
    {
        const int e0  = tid * 4;
        const int row = rb + (e0 >> 5);
        const int col = cb + (e0 & 31);
        float* sp32 = sf32 + (size_t)row * SSZ + col;
        st_coh_f32(sp32 + 0, 0.f); st_coh_f32(sp32 + 1, 0.f);
        st_coh_f32(sp32 + 2, 0.f); st_coh_f32(sp32 + 3, 0.f);
        __bf16* sp = sBuf + (size_t)row * SSZ + col;
        if (c < 2) {
            const float* xp = x + (size_t)row * INSZ + col;
            #pragma unroll
            for (int i = 0; i < 4; ++i)
                st_coh_u16(sp + i, __builtin_bit_cast(unsigned short, (__bf16)xp[i]));
        } else {
            #pragma unroll
            for (int i = 0; i < 4; ++i)
                st_coh_u16(sp + i, __builtin_bit_cast(unsigned short, (__bf16)0.f));
        }
    }

    group_barrier(flags, g, c, 1u, tid);

    // ---- per-thread geometry ----
    const int lane  = tid & 63;
    const int wv    = tid >> 6;
    const int mh    = wv >> 1;                       // row half
    const int nh    = wv & 1;                        // col half
    const int kgrp  = lane >> 4;
    const int kbyte = kgrp * 16;
    const int aloc  = mh * 16 + (lane & 15);         // A row within group slice
    const int aswz  = (aloc & 7) << 4;
    const char* As_rd = As + aloc * 1024;
    const int lc    = nh * 16 + (lane & 15);         // local col 0..31
    const int bswz  = (lc & 7) << 4;
    const char* Bw1 = W1s + lc * 2048;
    const char* Bw2 = W2s + lc * 2048;
    const float bias1 = b1[cb + lc];
    const float bias2 = b2[cb + lc];
    const int drow0 = rb + mh * 16 + kgrp * 4;       // C/D row base
    const int dcol  = cb + lc;                       // C/D col
    const float P = 0.97f, OMP = 1.0f - 0.97f;

    // staging role: thread covers row r (of 32), octant o (64 k-elems)
    const int r = tid >> 3;
    const int o = tid & 7;
    const __bf16* pS = sBuf + (size_t)(rb + r) * SSZ + o * 64;
    const __bf16* pH = hBuf + (size_t)(rb + r) * SSZ + o * 64;

    for (int t = 0; t < NSTEP; ++t) {
        // ---- phase 1: h = |s @ W1^T + b1| ----
        f32x4 acc[4];
        #pragma unroll
        for (int i = 0; i < 4; ++i) acc[i] = (f32x4){0.f, 0.f, 0.f, 0.f};
        run_phase(pS, As, r, o, As_rd, Bw1, kbyte, aswz, bswz, acc);
        f32x4 h4 = (acc[0] + acc[1]) + (acc[2] + acc[3]);
        #pragma unroll
        for (int j = 0; j < 4; ++j) {
            float hv = fabsf(h4[j] + bias1);
            st_coh_u16(hBuf + (size_t)(drow0 + j) * SSZ + dcol,
                       __builtin_bit_cast(unsigned short, (__bf16)hv));
        }
        group_barrier(flags, g, c, (unsigned)(2 + 2 * t), tid);

        // ---- phase 2: S' = p*s + (1-p)*(h @ W2^T + b2) ----
        #pragma unroll
        for (int i = 0; i < 4; ++i) acc[i] = (f32x4){0.f, 0.f, 0.f, 0.f};
        run_phase(pH, As, r, o, As_rd, Bw2, kbyte, aswz, bswz, acc);
        f32x4 u4 = (acc[0] + acc[1]) + (acc[2] + acc[3]);

        const float* srd = sf32 + (size_t)(t & 1) * (BATCH * SSZ);
        float*       swr = sf32 + (size_t)((t + 1) & 1) * (BATCH * SSZ);
        float sp[4];
        if (c < 2) {  // shifted-in x_t columns: exact fp32 from input (read-only)
            const float* xp = x + (size_t)t * (BATCH * INSZ);
            #pragma unroll
            for (int j = 0; j < 4; ++j) sp[j] = xp[(size_t)(drow0 + j) * INSZ + dcol];
        } else {      // fp32 master from WG(g,c-2), via L3
            ld_coh_f32x4s(&srd[(size_t)(drow0 + 0) * SSZ + (dcol - 64)],
                          &srd[(size_t)(drow0 + 1) * SSZ + (dcol - 64)],
                          &srd[(size_t)(drow0 + 2) * SSZ + (dcol - 64)],
                          &srd[(size_t)(drow0 + 3) * SSZ + (dcol - 64)],
                          sp[0], sp[1], sp[2], sp[3]);
        }
        #pragma unroll
        for (int j = 0; j < 4; ++j) {
            const int row = drow0 + j;
            const float snew = P * sp[j] + OMP * (u4[j] + bias2);
            st_coh_f32(&swr[(size_t)row * SSZ + dcol], snew);       // fp32 master
            if (c < 30)                                             // shifted bf16 publish
                st_coh_u16(sBuf + (size_t)row * SSZ + (dcol + 64),
                           __builtin_bit_cast(unsigned short, (__bf16)snew));
            else if (t == NSTEP - 1)                                // final output cols
                dout[row * 64 + (dcol - 960)] = snew;
        }
        if (c < 2 && t < NSTEP - 1) {  // blocks 0,1 of s_{t+1} = x_{t+1}
            #pragma unroll
            for (int j = 0; j < 4; ++j) {
                const int row = drow0 + j;
                st_coh_u16(sBuf + (size_t)row * SSZ + dcol,
                           __builtin_bit_cast(unsigned short,
                               (__bf16)x[(size_t)(t + 1) * (BATCH * INSZ) +
                                         (size_t)row * INSZ + dcol]));
            }
        }
        if (t < NSTEP - 1)
            group_barrier(flags, g, c, (unsigned)(3 + 2 * t), tid);
    }
}

extern "C" void kernel_launch(void* const* d_in, const int* in_sizes, int n_in,
                              void* d_out, int out_size, void* d_ws, size_t ws_size,
                              hipStream_t stream)
{
    const float* x  = (const float*)d_in[0];
    const float* W1 = (const float*)d_in[1];
    const float* b1 = (const float*)d_in[2];
    const float* W2 = (const float*)d_in[3];
    const float* b2 = (const float*)d_in[4];
    float* dout = (float*)d_out;

    char* ws = (char*)d_ws;
    __bf16*   sBuf  = (__bf16*)(ws);                 // 512 KiB: shifted s_t, bf16
    __bf16*   hBuf  = (__bf16*)(ws + (512 << 10));   // 512 KiB: h, bf16
    float*    sf32  = (float*)(ws + (1 << 20));      // 2 MiB: fp32 S ping-pong
    unsigned* flags = (unsigned*)(ws + (3 << 20));   // 16 KiB: padded flags

    (void)in_sizes; (void)n_in; (void)out_size; (void)ws_size;

    hipFuncSetAttribute(reinterpret_cast<const void*>(&resrnn_kernel),
                        hipFuncAttributeMaxDynamicSharedMemorySize, 163840);
    hipLaunchKernelGGL(resrnn_kernel, dim3(256), dim3(256), 163840, stream,
                       x, W1, b1, W2, b2, sBuf, hBuf, sf32, flags, dout);
}